// Round 1
// baseline (2339.551 us; speedup 1.0000x reference)
//
#include <hip/hip_runtime.h>
#include <math.h>

// MoE router: logits = (x @ W1^T + b1) @ W2^T + b2; softmax; top-2; masks.
// N=32768 tokens, D=1024, D/2=512 hidden, E=8 experts, K=2.
// Fused single kernel: block computes 64 rows x all 512 hidden cols (fp32
// vector GEMM -- no fp32 MFMA on CDNA4), then router tail in-block.

#define N_TOK 32768
#define D_IN  1024
#define D_H   512
#define N_EXP 8

#define BM      64
#define BK      16
#define THREADS 512

__global__ void moe_router_fused(const float* __restrict__ x,
                                 const float* __restrict__ W1,
                                 const float* __restrict__ b1,
                                 const float* __restrict__ W2,
                                 const float* __restrict__ b2,
                                 float* __restrict__ out)
{
    __shared__ float A_s[BK][BM];        // x tile,  [k][m]
    __shared__ float B_s[BK][D_H];       // W1 tile, [k][n]
    __shared__ float W2_s[N_EXP * D_H];
    __shared__ float b1_s[D_H];
    __shared__ float b2_s[N_EXP];

    const int t    = threadIdx.x;
    const int wave = t >> 6;
    const int lane = t & 63;
    const int m0   = blockIdx.x * BM;

    float acc[8][8];
#pragma unroll
    for (int r = 0; r < 8; ++r)
#pragma unroll
        for (int j = 0; j < 8; ++j) acc[r][j] = 0.f;

    // staging registers (register double-buffer: load k+1 while computing k)
    float4 aReg;
    float4 bReg[4];
    const int am  = t & 63;   // A: row within tile (threads < 256)
    const int akc = t >> 6;   // A: which float4 along k (0..3 for t<256)

    // ---- prologue load (tile 0) ----
    {
        const int k0 = 0;
        if (t < 256)
            aReg = *(const float4*)&x[(size_t)(m0 + am) * D_IN + k0 + akc * 4];
#pragma unroll
        for (int kc = 0; kc < 4; ++kc)
            bReg[kc] = *(const float4*)&W1[(size_t)t * D_IN + k0 + kc * 4];
    }

    const int NT = D_IN / BK;  // 64 k-tiles
    for (int kt = 0; kt < NT; ++kt) {
        // write staged regs -> LDS
        if (t < 256) {
            A_s[akc * 4 + 0][am] = aReg.x;
            A_s[akc * 4 + 1][am] = aReg.y;
            A_s[akc * 4 + 2][am] = aReg.z;
            A_s[akc * 4 + 3][am] = aReg.w;
        }
#pragma unroll
        for (int kc = 0; kc < 4; ++kc) {
            B_s[kc * 4 + 0][t] = bReg[kc].x;
            B_s[kc * 4 + 1][t] = bReg[kc].y;
            B_s[kc * 4 + 2][t] = bReg[kc].z;
            B_s[kc * 4 + 3][t] = bReg[kc].w;
        }
        __syncthreads();

        // prefetch next tile into regs (overlaps with compute below)
        if (kt + 1 < NT) {
            const int k0 = (kt + 1) * BK;
            if (t < 256)
                aReg = *(const float4*)&x[(size_t)(m0 + am) * D_IN + k0 + akc * 4];
#pragma unroll
            for (int kc = 0; kc < 4; ++kc)
                bReg[kc] = *(const float4*)&W1[(size_t)t * D_IN + k0 + kc * 4];
        }

        // compute: 8x8 outer product per thread, 16 k-steps
#pragma unroll
        for (int k = 0; k < BK; ++k) {
            float4 a0  = *(const float4*)&A_s[k][wave * 8];
            float4 a1  = *(const float4*)&A_s[k][wave * 8 + 4];
            float4 bb0 = *(const float4*)&B_s[k][lane * 8];
            float4 bb1 = *(const float4*)&B_s[k][lane * 8 + 4];
            float av[8] = {a0.x, a0.y, a0.z, a0.w, a1.x, a1.y, a1.z, a1.w};
            float bv[8] = {bb0.x, bb0.y, bb0.z, bb0.w, bb1.x, bb1.y, bb1.z, bb1.w};
#pragma unroll
            for (int r = 0; r < 8; ++r)
#pragma unroll
                for (int j = 0; j < 8; ++j)
                    acc[r][j] = fmaf(av[r], bv[j], acc[r][j]);
        }
        __syncthreads();
    }

    // ---- epilogue: stage W2/b1/b2 (B_s dead now) ----
    {
        float4*       w2s4 = (float4*)W2_s;
        const float4* w2g4 = (const float4*)W2;
        w2s4[t * 2]     = w2g4[t * 2];
        w2s4[t * 2 + 1] = w2g4[t * 2 + 1];
        if (t < D_H / 4) ((float4*)b1_s)[t] = ((const float4*)b1)[t];
        if (t < N_EXP) b2_s[t] = b2[t];
    }
    __syncthreads();

    float* out_logits = out;
    float* out_w      = out + (size_t)N_TOK * N_EXP;
    float* out_i      = out_w + (size_t)N_TOK * 2;
    float* out_m      = out_i + (size_t)N_TOK * 2;

#pragma unroll 1
    for (int r = 0; r < 8; ++r) {
        const int row = m0 + wave * 8 + r;

        // h for this thread's 8 columns (n = lane*8 + j)
        float h[8];
        {
            const float4* b1p = (const float4*)&b1_s[lane * 8];
            float4 c0 = b1p[0], c1 = b1p[1];
            float bl[8] = {c0.x, c0.y, c0.z, c0.w, c1.x, c1.y, c1.z, c1.w};
#pragma unroll
            for (int j = 0; j < 8; ++j) h[j] = acc[r][j] + bl[j];
        }

        // partial logits: 8 experts x this lane's 8 cols
        float pl[8];
#pragma unroll
        for (int e = 0; e < 8; ++e) {
            const float4* wp = (const float4*)&W2_s[e * D_H + lane * 8];
            float4 wa = wp[0], wb = wp[1];
            float wv[8] = {wa.x, wa.y, wa.z, wa.w, wb.x, wb.y, wb.z, wb.w};
            float s = 0.f;
#pragma unroll
            for (int j = 0; j < 8; ++j) s = fmaf(h[j], wv[j], s);
            pl[e] = s;
        }

        // 64-lane butterfly allreduce per expert
#pragma unroll
        for (int e = 0; e < 8; ++e) {
            float s = pl[e];
#pragma unroll
            for (int off = 1; off < 64; off <<= 1)
                s += __shfl_xor(s, off);
            pl[e] = s + b2_s[e];
        }

        // top-2 (ties -> lower index, matching jax.lax.top_k)
        float v1 = pl[0]; int i1 = 0;
#pragma unroll
        for (int e = 1; e < 8; ++e)
            if (pl[e] > v1) { v1 = pl[e]; i1 = e; }
        float v2 = -3.4e38f; int i2 = 0;
#pragma unroll
        for (int e = 0; e < 8; ++e)
            if (e != i1 && pl[e] > v2) { v2 = pl[e]; i2 = e; }

        // normalized top-2 weights: softmax denominator cancels
        const float rr   = expf(v2 - v1);        // <= 1
        const float wden = 1.f / (1.f + rr);
        const float w1v  = wden;
        const float w2v  = rr * wden;

        if (lane == 0) {
            float4 lo = {pl[0], pl[1], pl[2], pl[3]};
            float4 hi = {pl[4], pl[5], pl[6], pl[7]};
            *(float4*)&out_logits[(size_t)row * 8]     = lo;
            *(float4*)&out_logits[(size_t)row * 8 + 4] = hi;
            float2 wv = {w1v, w2v};
            *(float2*)&out_w[(size_t)row * 2] = wv;
            float2 iv = {(float)i1, (float)i2};
            *(float2*)&out_i[(size_t)row * 2] = iv;
        }
        // dense mask write: lanes 0..15 cover (e,k); all elements written
        if (lane < 16) {
            const int e  = lane >> 1;
            const int kk = lane & 1;
            const int sel = kk ? i2 : i1;
            out_m[((size_t)(e * 2 + kk)) * N_TOK + row] = (sel == e) ? 1.0f : 0.0f;
        }
    }
}

extern "C" void kernel_launch(void* const* d_in, const int* in_sizes, int n_in,
                              void* d_out, int out_size, void* d_ws, size_t ws_size,
                              hipStream_t stream) {
    const float* x  = (const float*)d_in[0];
    const float* W1 = (const float*)d_in[1];
    const float* b1 = (const float*)d_in[2];
    const float* W2 = (const float*)d_in[3];
    const float* b2 = (const float*)d_in[4];
    float* out = (float*)d_out;

    moe_router_fused<<<N_TOK / BM, THREADS, 0, stream>>>(x, W1, b1, W2, b2, out);
}

// Round 2
// 1963.547 us; speedup vs baseline: 1.1915x; 1.1915x over previous
//
#include <hip/hip_runtime.h>
#include <math.h>

// MoE router: logits = (x @ W1^T + b1) @ W2^T + b2; softmax; top-2; masks.
// N=32768 tokens, D=1024, D/2=512 hidden, E=8 experts, K=2.
// Block = 64 rows x all 512 hidden cols, fp32 vector GEMM (no fp32 MFMA on
// CDNA4), router tail fused in-block. All register arrays statically indexed
// (rule #20: runtime-indexed arrays spill to scratch -- round-1 failure mode).

#define N_TOK 32768
#define D_IN  1024
#define D_H   512
#define N_EXP 8

#define BM      64
#define BK      16
#define THREADS 512

__global__ __launch_bounds__(THREADS, 4)  // cap VGPR at 128 -> 2 blocks/CU
void moe_router_fused(const float* __restrict__ x,
                      const float* __restrict__ W1,
                      const float* __restrict__ b1,
                      const float* __restrict__ W2,
                      const float* __restrict__ b2,
                      float* __restrict__ out)
{
    __shared__ float A_s[BK][BM];        // x tile,  [k][m]
    __shared__ float B_s[BK][D_H];       // W1 tile, [k][n]
    __shared__ float W2_s[N_EXP * D_H];
    __shared__ float b1_s[D_H];
    __shared__ float b2_s[N_EXP];

    const int t    = threadIdx.x;
    const int wave = t >> 6;
    const int lane = t & 63;
    const int m0   = blockIdx.x * BM;
    // this thread's 8 hidden columns: c0..c0+3 and 256+c0..256+c0+3
    // (float4 at byte offset lane*16 -> contiguous across the wave -> no
    //  LDS bank conflicts, vs round-1's lane*32 stride = 16-way conflict)
    const int c0 = lane * 4;

    float acc[8][8];
#pragma unroll
    for (int r = 0; r < 8; ++r)
#pragma unroll
        for (int j = 0; j < 8; ++j) acc[r][j] = 0.f;

    // staging registers (register double-buffer: load k+1 while computing k)
    float4 aReg;
    float4 bReg[4];
    const int am  = t & 63;   // A: row within tile (threads < 256)
    const int akc = t >> 6;   // A: which float4 along k (0..3 for t<256)

    // ---- prologue load (tile 0) ----
    if (t < 256)
        aReg = *(const float4*)&x[(size_t)(m0 + am) * D_IN + akc * 4];
#pragma unroll
    for (int kc = 0; kc < 4; ++kc)
        bReg[kc] = *(const float4*)&W1[(size_t)t * D_IN + kc * 4];

    const int NT = D_IN / BK;  // 64 k-tiles
    for (int kt = 0; kt < NT; ++kt) {
        // write staged regs -> LDS
        if (t < 256) {
            A_s[akc * 4 + 0][am] = aReg.x;
            A_s[akc * 4 + 1][am] = aReg.y;
            A_s[akc * 4 + 2][am] = aReg.z;
            A_s[akc * 4 + 3][am] = aReg.w;
        }
#pragma unroll
        for (int kc = 0; kc < 4; ++kc) {
            B_s[kc * 4 + 0][t] = bReg[kc].x;
            B_s[kc * 4 + 1][t] = bReg[kc].y;
            B_s[kc * 4 + 2][t] = bReg[kc].z;
            B_s[kc * 4 + 3][t] = bReg[kc].w;
        }
        __syncthreads();

        // prefetch next tile into regs (overlaps with compute below)
        if (kt + 1 < NT) {
            const int k0 = (kt + 1) * BK;
            if (t < 256)
                aReg = *(const float4*)&x[(size_t)(m0 + am) * D_IN + k0 + akc * 4];
#pragma unroll
            for (int kc = 0; kc < 4; ++kc)
                bReg[kc] = *(const float4*)&W1[(size_t)t * D_IN + k0 + kc * 4];
        }

        // compute: 8x8 outer product per thread, 16 k-steps
#pragma unroll
        for (int k = 0; k < BK; ++k) {
            float4 a0  = *(const float4*)&A_s[k][wave * 8];       // broadcast
            float4 a1  = *(const float4*)&A_s[k][wave * 8 + 4];   // broadcast
            float4 bb0 = *(const float4*)&B_s[k][c0];             // contiguous
            float4 bb1 = *(const float4*)&B_s[k][256 + c0];       // contiguous
            float av[8] = {a0.x, a0.y, a0.z, a0.w, a1.x, a1.y, a1.z, a1.w};
            float bv[8] = {bb0.x, bb0.y, bb0.z, bb0.w, bb1.x, bb1.y, bb1.z, bb1.w};
#pragma unroll
            for (int r = 0; r < 8; ++r)
#pragma unroll
                for (int j = 0; j < 8; ++j)
                    acc[r][j] = fmaf(av[r], bv[j], acc[r][j]);
        }
        __syncthreads();
    }

    // ---- epilogue: stage W2/b1/b2 ----
    {
        float4*       w2s4 = (float4*)W2_s;
        const float4* w2g4 = (const float4*)W2;
        w2s4[t * 2]     = w2g4[t * 2];
        w2s4[t * 2 + 1] = w2g4[t * 2 + 1];
        if (t < D_H / 4) ((float4*)b1_s)[t] = ((const float4*)b1)[t];
        if (t < N_EXP) b2_s[t] = b2[t];
    }
    __syncthreads();

    float* out_logits = out;
    float* out_w      = out + (size_t)N_TOK * N_EXP;
    float* out_i      = out_w + (size_t)N_TOK * 2;
    float* out_m      = out_i + (size_t)N_TOK * 2;

    // h = acc + b1 (in place; 8 bias values for this thread's columns)
    {
        float4 c0v = *(const float4*)&b1_s[c0];
        float4 c1v = *(const float4*)&b1_s[256 + c0];
        float bl[8] = {c0v.x, c0v.y, c0v.z, c0v.w, c1v.x, c1v.y, c1v.z, c1v.w};
#pragma unroll
        for (int r = 0; r < 8; ++r)
#pragma unroll
            for (int j = 0; j < 8; ++j) acc[r][j] += bl[j];
    }

    // Expert-outer: for each expert, dot + 64-lane butterfly allreduce per
    // row; maintain running top-2 per row (strict > == ties to lower index,
    // matching jax.lax.top_k). All arrays statically indexed via unroll.
    float tv1[8], tv2[8];
    int   ti1[8], ti2[8];
#pragma unroll
    for (int r = 0; r < 8; ++r) {
        tv1[r] = -3.4e38f; tv2[r] = -3.4e38f; ti1[r] = 0; ti2[r] = 0;
    }

#pragma unroll
    for (int e = 0; e < N_EXP; ++e) {
        float4 wa = *(const float4*)&W2_s[e * D_H + c0];
        float4 wb = *(const float4*)&W2_s[e * D_H + 256 + c0];
        float wv[8] = {wa.x, wa.y, wa.z, wa.w, wb.x, wb.y, wb.z, wb.w};
        const float be = b2_s[e];
#pragma unroll
        for (int r = 0; r < 8; ++r) {
            float s = 0.f;
#pragma unroll
            for (int j = 0; j < 8; ++j) s = fmaf(acc[r][j], wv[j], s);
            // 64-lane butterfly allreduce: every lane gets the full sum
#pragma unroll
            for (int off = 1; off < 64; off <<= 1)
                s += __shfl_xor(s, off);
            s += be;
            if (lane == 0)
                out_logits[(size_t)(m0 + wave * 8 + r) * N_EXP + e] = s;
            // running top-2 update
            if (s > tv1[r]) {
                tv2[r] = tv1[r]; ti2[r] = ti1[r];
                tv1[r] = s;      ti1[r] = e;
            } else if (s > tv2[r]) {
                tv2[r] = s;      ti2[r] = e;
            }
        }
    }

#pragma unroll
    for (int r = 0; r < 8; ++r) {
        const int row = m0 + wave * 8 + r;
        // normalized top-2 weights: softmax denominator cancels
        const float rr   = expf(tv2[r] - tv1[r]);     // <= 1
        const float wden = 1.f / (1.f + rr);
        if (lane == 0) {
            float2 wv = {wden, rr * wden};
            *(float2*)&out_w[(size_t)row * 2] = wv;
            float2 iv = {(float)ti1[r], (float)ti2[r]};
            *(float2*)&out_i[(size_t)row * 2] = iv;
        }
        // dense mask write: lanes 0..15 cover (e,k); every element written
        if (lane < 16) {
            const int e   = lane >> 1;
            const int kk  = lane & 1;
            const int sel = kk ? ti2[r] : ti1[r];
            out_m[((size_t)(e * 2 + kk)) * N_TOK + row] = (sel == e) ? 1.0f : 0.0f;
        }
    }
}

extern "C" void kernel_launch(void* const* d_in, const int* in_sizes, int n_in,
                              void* d_out, int out_size, void* d_ws, size_t ws_size,
                              hipStream_t stream) {
    const float* x  = (const float*)d_in[0];
    const float* W1 = (const float*)d_in[1];
    const float* b1 = (const float*)d_in[2];
    const float* W2 = (const float*)d_in[3];
    const float* b2 = (const float*)d_in[4];
    float* out = (float*)d_out;

    moe_router_fused<<<N_TOK / BM, THREADS, 0, stream>>>(x, W1, b1, W2, b2, out);
}

// Round 3
// 442.660 us; speedup vs baseline: 5.2852x; 4.4358x over previous
//
#include <hip/hip_runtime.h>
#include <math.h>

// MoE router: logits = (x @ W1^T + b1) @ W2^T + b2; softmax; top-2; masks.
// N=32768 tokens, D=1024, D/2=512 hidden, E=8 experts, K=2.
// Block = 64 rows x all 512 hidden cols, fp32 vector GEMM (no fp32 MFMA on
// CDNA4), router tail fused in-block.
//
// Round-3 change: __launch_bounds__(512, 2). Rounds 1/2 compiled with a
// 64-VGPR cap (2nd arg behaves as min-BLOCKS/CU on this toolchain; 4 blocks
// x 8 waves = 32 waves/CU -> 64 VGPRs) which spilled acc[8][8] to scratch
// once per k-tile: 5.3 GB of scratch writes = the entire 2 ms runtime.
// 2 blocks/CU -> 4 waves/SIMD -> 128-VGPR cap, acc fits in registers.

#define N_TOK 32768
#define D_IN  1024
#define D_H   512
#define N_EXP 8

#define BM      64
#define BK      16
#define THREADS 512

__global__ __launch_bounds__(THREADS, 2)  // 2 blocks/CU -> 128-VGPR cap
void moe_router_fused(const float* __restrict__ x,
                      const float* __restrict__ W1,
                      const float* __restrict__ b1,
                      const float* __restrict__ W2,
                      const float* __restrict__ b2,
                      float* __restrict__ out)
{
    __shared__ float A_s[BK][BM];        // x tile,  [k][m]
    __shared__ float B_s[BK][D_H];       // W1 tile, [k][n]
    __shared__ float W2_s[N_EXP * D_H];
    __shared__ float b1_s[D_H];
    __shared__ float b2_s[N_EXP];

    const int t    = threadIdx.x;
    const int wave = t >> 6;
    const int lane = t & 63;
    const int m0   = blockIdx.x * BM;
    // this thread's 8 hidden columns: c0..c0+3 and 256+c0..256+c0+3
    // (float4 at byte offset lane*16 -> contiguous across the wave -> no
    //  LDS bank conflicts)
    const int c0 = lane * 4;

    float acc[8][8];
#pragma unroll
    for (int r = 0; r < 8; ++r)
#pragma unroll
        for (int j = 0; j < 8; ++j) acc[r][j] = 0.f;

    // staging registers (register double-buffer: load k+1 while computing k)
    float4 aReg;
    float4 bReg[4];
    const int am  = t & 63;   // A: row within tile (threads < 256)
    const int akc = t >> 6;   // A: which float4 along k (0..3 for t<256)

    // ---- prologue load (tile 0) ----
    if (t < 256)
        aReg = *(const float4*)&x[(size_t)(m0 + am) * D_IN + akc * 4];
#pragma unroll
    for (int kc = 0; kc < 4; ++kc)
        bReg[kc] = *(const float4*)&W1[(size_t)t * D_IN + kc * 4];

    const int NT = D_IN / BK;  // 64 k-tiles
    for (int kt = 0; kt < NT; ++kt) {
        // write staged regs -> LDS
        if (t < 256) {
            A_s[akc * 4 + 0][am] = aReg.x;
            A_s[akc * 4 + 1][am] = aReg.y;
            A_s[akc * 4 + 2][am] = aReg.z;
            A_s[akc * 4 + 3][am] = aReg.w;
        }
#pragma unroll
        for (int kc = 0; kc < 4; ++kc) {
            B_s[kc * 4 + 0][t] = bReg[kc].x;
            B_s[kc * 4 + 1][t] = bReg[kc].y;
            B_s[kc * 4 + 2][t] = bReg[kc].z;
            B_s[kc * 4 + 3][t] = bReg[kc].w;
        }
        __syncthreads();

        // prefetch next tile into regs (overlaps with compute below)
        if (kt + 1 < NT) {
            const int k0 = (kt + 1) * BK;
            if (t < 256)
                aReg = *(const float4*)&x[(size_t)(m0 + am) * D_IN + k0 + akc * 4];
#pragma unroll
            for (int kc = 0; kc < 4; ++kc)
                bReg[kc] = *(const float4*)&W1[(size_t)t * D_IN + k0 + kc * 4];
        }

        // compute: 8x8 outer product per thread, 16 k-steps
#pragma unroll
        for (int k = 0; k < BK; ++k) {
            float4 a0  = *(const float4*)&A_s[k][wave * 8];       // broadcast
            float4 a1  = *(const float4*)&A_s[k][wave * 8 + 4];   // broadcast
            float4 bb0 = *(const float4*)&B_s[k][c0];             // contiguous
            float4 bb1 = *(const float4*)&B_s[k][256 + c0];       // contiguous
            float av[8] = {a0.x, a0.y, a0.z, a0.w, a1.x, a1.y, a1.z, a1.w};
            float bv[8] = {bb0.x, bb0.y, bb0.z, bb0.w, bb1.x, bb1.y, bb1.z, bb1.w};
#pragma unroll
            for (int r = 0; r < 8; ++r)
#pragma unroll
                for (int j = 0; j < 8; ++j)
                    acc[r][j] = fmaf(av[r], bv[j], acc[r][j]);
        }
        __syncthreads();
    }

    // ---- epilogue: stage W2/b1/b2 ----
    {
        float4*       w2s4 = (float4*)W2_s;
        const float4* w2g4 = (const float4*)W2;
        w2s4[t * 2]     = w2g4[t * 2];
        w2s4[t * 2 + 1] = w2g4[t * 2 + 1];
        if (t < D_H / 4) ((float4*)b1_s)[t] = ((const float4*)b1)[t];
        if (t < N_EXP) b2_s[t] = b2[t];
    }
    __syncthreads();

    float* out_logits = out;
    float* out_w      = out + (size_t)N_TOK * N_EXP;
    float* out_i      = out_w + (size_t)N_TOK * 2;
    float* out_m      = out_i + (size_t)N_TOK * 2;

    // h = acc + b1 (in place; 8 bias values for this thread's columns)
    {
        float4 c0v = *(const float4*)&b1_s[c0];
        float4 c1v = *(const float4*)&b1_s[256 + c0];
        float bl[8] = {c0v.x, c0v.y, c0v.z, c0v.w, c1v.x, c1v.y, c1v.z, c1v.w};
#pragma unroll
        for (int r = 0; r < 8; ++r)
#pragma unroll
            for (int j = 0; j < 8; ++j) acc[r][j] += bl[j];
    }

    // Expert-outer: for each expert, dot + 64-lane butterfly allreduce per
    // row; maintain running top-2 per row (strict > == ties to lower index,
    // matching jax.lax.top_k). All arrays statically indexed via unroll.
    float tv1[8], tv2[8];
    int   ti1[8], ti2[8];
#pragma unroll
    for (int r = 0; r < 8; ++r) {
        tv1[r] = -3.4e38f; tv2[r] = -3.4e38f; ti1[r] = 0; ti2[r] = 0;
    }

#pragma unroll
    for (int e = 0; e < N_EXP; ++e) {
        float4 wa = *(const float4*)&W2_s[e * D_H + c0];
        float4 wb = *(const float4*)&W2_s[e * D_H + 256 + c0];
        float wv[8] = {wa.x, wa.y, wa.z, wa.w, wb.x, wb.y, wb.z, wb.w};
        const float be = b2_s[e];
#pragma unroll
        for (int r = 0; r < 8; ++r) {
            float s = 0.f;
#pragma unroll
            for (int j = 0; j < 8; ++j) s = fmaf(acc[r][j], wv[j], s);
            // 64-lane butterfly allreduce: every lane gets the full sum
#pragma unroll
            for (int off = 1; off < 64; off <<= 1)
                s += __shfl_xor(s, off);
            s += be;
            if (lane == 0)
                out_logits[(size_t)(m0 + wave * 8 + r) * N_EXP + e] = s;
            // running top-2 update
            if (s > tv1[r]) {
                tv2[r] = tv1[r]; ti2[r] = ti1[r];
                tv1[r] = s;      ti1[r] = e;
            } else if (s > tv2[r]) {
                tv2[r] = s;      ti2[r] = e;
            }
        }
    }

#pragma unroll
    for (int r = 0; r < 8; ++r) {
        const int row = m0 + wave * 8 + r;
        // normalized top-2 weights: softmax denominator cancels
        const float rr   = expf(tv2[r] - tv1[r]);     // <= 1
        const float wden = 1.f / (1.f + rr);
        if (lane == 0) {
            float2 wv = {wden, rr * wden};
            *(float2*)&out_w[(size_t)row * 2] = wv;
            float2 iv = {(float)ti1[r], (float)ti2[r]};
            *(float2*)&out_i[(size_t)row * 2] = iv;
        }
        // dense mask write: lanes 0..15 cover (e,k); every element written
        if (lane < 16) {
            const int e   = lane >> 1;
            const int kk  = lane & 1;
            const int sel = kk ? ti2[r] : ti1[r];
            out_m[((size_t)(e * 2 + kk)) * N_TOK + row] = (sel == e) ? 1.0f : 0.0f;
        }
    }
}

extern "C" void kernel_launch(void* const* d_in, const int* in_sizes, int n_in,
                              void* d_out, int out_size, void* d_ws, size_t ws_size,
                              hipStream_t stream) {
    const float* x  = (const float*)d_in[0];
    const float* W1 = (const float*)d_in[1];
    const float* b1 = (const float*)d_in[2];
    const float* W2 = (const float*)d_in[3];
    const float* b2 = (const float*)d_in[4];
    float* out = (float*)d_out;

    moe_router_fused<<<N_TOK / BM, THREADS, 0, stream>>>(x, W1, b1, W2, b2, out);
}

// Round 4
// 192.372 us; speedup vs baseline: 12.1616x; 2.3011x over previous
//
#include <hip/hip_runtime.h>
#include <math.h>

// MoE router on MFMA: logits = (x @ W1^T + b1) @ W2^T + b2; softmax; top-2; masks.
// N=32768, D=1024, D_H=512, E=8, K=2.
//
// fp32 has no MFMA on CDNA4 -> split-fp16 trick: x = xh + xl, W1 = wh + wl
// (residuals exact in fp32; fp16 keeps 11+11 bits), compute
//   h = xh*wh + xl*wh + xh*wl   (3 MFMA passes, fp32 accumulate)
// dropped xl*wl ~ 2^-22 relative -> logit error ~5e-7, below fp32 reorder noise.
//
// Pre-kernel splits W1 ONCE into d_ws, pre-packed in 32x32x16 fragment order:
// frag slot s = kt*1024 + ctg*64 + lane holds W1[n=32*ctg+(lane&31)][k=16*kt+8*(lane>>5)+0..7]
// -> main kernel B-staging is pure global_load_lds (16B, linear LDS).

#define N_TOK 32768
#define D_IN  1024
#define D_H   512
#define N_EXP 8

#define BM      64
#define BK      16
#define THREADS 512
#define NKT     (D_IN / BK)   // 64 k-tiles
#define WSLOTS  (NKT * 1024)  // W1 frag slots total (per hi/lo): 65536

typedef _Float16 f16;
typedef __attribute__((ext_vector_type(8)))  _Float16 f16x8;
typedef __attribute__((ext_vector_type(16))) float    f32x16;

#define MFMA(a, b, c) __builtin_amdgcn_mfma_f32_32x32x16_f16((a), (b), (c), 0, 0, 0)

#define GLOAD16(gsrc, ldst)                                                    \
    __builtin_amdgcn_global_load_lds(                                          \
        (const __attribute__((address_space(1))) void*)(gsrc),                 \
        (__attribute__((address_space(3))) void*)(ldst), 16, 0, 0)

__device__ inline void split8(const float4& a0, const float4& a1,
                              f16x8& hi, f16x8& lo) {
    float v[8] = {a0.x, a0.y, a0.z, a0.w, a1.x, a1.y, a1.z, a1.w};
#pragma unroll
    for (int j = 0; j < 8; ++j) {
        _Float16 h = (_Float16)v[j];
        hi[j] = h;
        lo[j] = (_Float16)(v[j] - (float)h);   // exact residual in fp32
    }
}

// ---- pre-kernel: split W1 into hi/lo f16 fragments in ws ----
__global__ void split_w1(const float* __restrict__ W1,
                         f16* __restrict__ wsH, f16* __restrict__ wsL) {
    const int s = blockIdx.x * 256 + threadIdx.x;   // 0..65535
    const int kt  = s >> 10;
    const int ctg = (s >> 6) & 15;
    const int l   = s & 63;
    const int n   = ctg * 32 + (l & 31);
    const int k   = kt * BK + (l >> 5) * 8;
    const float* src = &W1[(size_t)n * D_IN + k];
    float4 a0 = *(const float4*)src;
    float4 a1 = *(const float4*)(src + 4);
    f16x8 hi, lo;
    split8(a0, a1, hi, lo);
    *(f16x8*)&wsH[(size_t)s * 8] = hi;
    *(f16x8*)&wsL[(size_t)s * 8] = lo;
}

// ---- main kernel ----
__global__ __launch_bounds__(THREADS, 2)   // 4 waves/SIMD -> 128-VGPR cap
void moe_router_mfma(const float* __restrict__ x,
                     const f16* __restrict__ wH,
                     const f16* __restrict__ wL,
                     const float* __restrict__ b1,
                     const float* __restrict__ W2,
                     const float* __restrict__ b2,
                     float* __restrict__ out)
{
    __shared__ __align__(16) f16 AhiS[128 * 8];            // 2 KB
    __shared__ __align__(16) f16 AloS[128 * 8];            // 2 KB
    __shared__ __align__(16) unsigned char Bbuf[32768];    // B hi|lo, reused as h_s
    __shared__ __align__(16) float W2s[N_EXP * D_H];       // 16 KB
    __shared__ __align__(16) float b1s[D_H];               // 2 KB
    __shared__ float b2s[N_EXP];

    f16*   BhiS = (f16*)Bbuf;              // 16 KB: 1024 frag slots
    f16*   BloS = (f16*)(Bbuf + 16384);    // 16 KB
    float* h_s  = (float*)Bbuf;            // epilogue: [16][512] fp32 = 32 KB

    const int t    = threadIdx.x;
    const int w    = t >> 6;
    const int lane = t & 63;
    const int m0   = blockIdx.x * BM;

    f32x16 acc00 = {}, acc01 = {}, acc10 = {}, acc11 = {};

    // A staging geometry (threads 0..127): rh = t>>6, row = 32rh + (l&31),
    // k-half = l>>5; frag slot index == t.
    const int rhA = t >> 6;
    const int alA = t & 63;
    const float* aSrc = x + (size_t)(m0 + rhA * 32 + (alA & 31)) * D_IN + (alA >> 5) * 8;

    for (int kt = 0; kt < NKT; ++kt) {
        // ---- stage ----
        if (t < 128) {
            float4 a0 = *(const float4*)(aSrc + kt * BK);
            float4 a1 = *(const float4*)(aSrc + kt * BK + 4);
            f16x8 hi, lo;
            split8(a0, a1, hi, lo);
            *(f16x8*)&AhiS[t * 8] = hi;
            *(f16x8*)&AloS[t * 8] = lo;
        }
        {
            const size_t base = (size_t)kt * 1024 * 8;
            // wave-uniform LDS base + lane*16 (HW rule); per-lane global src
            GLOAD16(wH + base + (size_t)t * 8,         &BhiS[(size_t)(w * 64) * 8]);
            GLOAD16(wH + base + (size_t)(512 + t) * 8, &BhiS[(size_t)(512 + w * 64) * 8]);
            GLOAD16(wL + base + (size_t)t * 8,         &BloS[(size_t)(w * 64) * 8]);
            GLOAD16(wL + base + (size_t)(512 + t) * 8, &BloS[(size_t)(512 + w * 64) * 8]);
        }
        __syncthreads();

        // ---- compute: wave owns rh={0,1} x ctg={2w,2w+1} ----
        f16x8 ah0 = *(const f16x8*)&AhiS[lane * 8];
        f16x8 ah1 = *(const f16x8*)&AhiS[(64 + lane) * 8];
        f16x8 al0 = *(const f16x8*)&AloS[lane * 8];
        f16x8 al1 = *(const f16x8*)&AloS[(64 + lane) * 8];
        {
            f16x8 bh = *(const f16x8*)&BhiS[((2 * w) * 64 + lane) * 8];
            f16x8 bl = *(const f16x8*)&BloS[((2 * w) * 64 + lane) * 8];
            acc00 = MFMA(ah0, bh, acc00);
            acc00 = MFMA(al0, bh, acc00);
            acc00 = MFMA(ah0, bl, acc00);
            acc10 = MFMA(ah1, bh, acc10);
            acc10 = MFMA(al1, bh, acc10);
            acc10 = MFMA(ah1, bl, acc10);
        }
        {
            f16x8 bh = *(const f16x8*)&BhiS[((2 * w + 1) * 64 + lane) * 8];
            f16x8 bl = *(const f16x8*)&BloS[((2 * w + 1) * 64 + lane) * 8];
            acc01 = MFMA(ah0, bh, acc01);
            acc01 = MFMA(al0, bh, acc01);
            acc01 = MFMA(ah0, bl, acc01);
            acc11 = MFMA(ah1, bh, acc11);
            acc11 = MFMA(al1, bh, acc11);
            acc11 = MFMA(ah1, bl, acc11);
        }
        __syncthreads();
    }

    // ---- epilogue: stage W2/b1/b2 ----
    ((float4*)W2s)[t * 2]     = ((const float4*)W2)[t * 2];
    ((float4*)W2s)[t * 2 + 1] = ((const float4*)W2)[t * 2 + 1];
    if (t < D_H / 4) ((float4*)b1s)[t] = ((const float4*)b1)[t];
    if (t < N_EXP) b2s[t] = b2[t];
    __syncthreads();

    // this thread's two output columns (C/D layout: col = lane&31)
    const int n0 = w * 64 + (lane & 31);
    const int n1 = n0 + 32;
    const float bn0 = b1s[n0];
    const float bn1 = b1s[n1];

    float* out_logits = out;
    float* out_w      = out + (size_t)N_TOK * N_EXP;
    float* out_i      = out_w + (size_t)N_TOK * 2;
    float* out_m      = out_i + (size_t)N_TOK * 2;

    // per 16-row group: scatter h to LDS, then router tail (round-2-verified
    // dot + 64-lane butterfly + running top-2).
    auto reduce_rows = [&](int g) {
#pragma unroll
        for (int rr2 = 0; rr2 < 2; ++rr2) {
            const int rl   = w + 8 * rr2;
            const int grow = m0 + g * 16 + rl;
            float4 ha = *(const float4*)&h_s[rl * 512 + lane * 4];
            float4 hb = *(const float4*)&h_s[rl * 512 + 256 + lane * 4];
            float v1 = -3.4e38f, v2 = -3.4e38f;
            int   i1 = 0, i2 = 0;
            float pls[8];
#pragma unroll
            for (int e = 0; e < N_EXP; ++e) {
                float4 wa = *(const float4*)&W2s[e * D_H + lane * 4];
                float4 wb = *(const float4*)&W2s[e * D_H + 256 + lane * 4];
                float s = ha.x * wa.x;
                s = fmaf(ha.y, wa.y, s);
                s = fmaf(ha.z, wa.z, s);
                s = fmaf(ha.w, wa.w, s);
                s = fmaf(hb.x, wb.x, s);
                s = fmaf(hb.y, wb.y, s);
                s = fmaf(hb.z, wb.z, s);
                s = fmaf(hb.w, wb.w, s);
#pragma unroll
                for (int off = 1; off < 64; off <<= 1)
                    s += __shfl_xor(s, off);
                s += b2s[e];
                pls[e] = s;
                if (s > v1)      { v2 = v1; i2 = i1; v1 = s; i1 = e; }
                else if (s > v2) { v2 = s;  i2 = e; }
            }
            const float rr   = expf(v2 - v1);
            const float wden = 1.f / (1.f + rr);
            if (lane == 0) {
                float4 lo4 = {pls[0], pls[1], pls[2], pls[3]};
                float4 hi4 = {pls[4], pls[5], pls[6], pls[7]};
                *(float4*)&out_logits[(size_t)grow * N_EXP]     = lo4;
                *(float4*)&out_logits[(size_t)grow * N_EXP + 4] = hi4;
                float2 wv = {wden, rr * wden};
                *(float2*)&out_w[(size_t)grow * 2] = wv;
                float2 iv = {(float)i1, (float)i2};
                *(float2*)&out_i[(size_t)grow * 2] = iv;
            }
            if (lane < 16) {
                const int e   = lane >> 1;
                const int kk  = lane & 1;
                const int sel = kk ? i2 : i1;
                out_m[((size_t)(e * 2 + kk)) * N_TOK + grow] = (sel == e) ? 1.0f : 0.0f;
            }
        }
    };

    // C/D layout (m74-verified): tile row = (reg&3) + 8*(reg>>2) + 4*(lane>>5).
    // Group g: rh = g>>1 (acc0x vs acc1x), half = g&1 (regs 0..7 vs 8..15);
    // in-group row = (rr&3) + 8*(rr>>2) + 4*(lane>>5).
#define DO_GROUP(AC0, AC1, HALF, G) do {                                       \
        _Pragma("unroll")                                                      \
        for (int rr = 0; rr < 8; ++rr) {                                       \
            const int rl = (rr & 3) + 8 * (rr >> 2) + 4 * (lane >> 5);         \
            h_s[rl * 512 + n0] = AC0[(HALF) * 8 + rr] + bn0;                   \
            h_s[rl * 512 + n1] = AC1[(HALF) * 8 + rr] + bn1;                   \
        }                                                                      \
        __syncthreads();                                                       \
        reduce_rows(G);                                                        \
        __syncthreads();                                                       \
    } while (0)

    DO_GROUP(acc00, acc01, 0, 0);
    DO_GROUP(acc00, acc01, 1, 1);
    DO_GROUP(acc10, acc11, 0, 2);
    DO_GROUP(acc10, acc11, 1, 3);
#undef DO_GROUP
}

extern "C" void kernel_launch(void* const* d_in, const int* in_sizes, int n_in,
                              void* d_out, int out_size, void* d_ws, size_t ws_size,
                              hipStream_t stream) {
    const float* x  = (const float*)d_in[0];
    const float* W1 = (const float*)d_in[1];
    const float* b1 = (const float*)d_in[2];
    const float* W2 = (const float*)d_in[3];
    const float* b2 = (const float*)d_in[4];
    float* out = (float*)d_out;

    f16* wsH = (f16*)d_ws;                       // 1 MB
    f16* wsL = wsH + (size_t)WSLOTS * 8;         // 1 MB

    split_w1<<<WSLOTS / 256, 256, 0, stream>>>(W1, wsH, wsL);
    moe_router_mfma<<<N_TOK / BM, THREADS, 0, stream>>>(x, wsH, wsL, b1, W2, b2, out);
}

// Round 5
// 141.315 us; speedup vs baseline: 16.5555x; 1.3613x over previous
//
#include <hip/hip_runtime.h>
#include <math.h>

// MoE router on MFMA: logits = (x @ W1^T + b1) @ W2^T + b2; softmax; top-2; masks.
// N=32768, D=1024, D_H=512, E=8, K=2.
//
// Split-fp16: x = xh+xl, W1 = wh+wl; h = xh*wh + xl*wh + xh*wl (3 MFMA passes,
// fp32 acc). W1 pre-split/pre-packed into fragment order in d_ws (verified r4).
//
// Round-5: BM=128 (grid=256 = 1 block/CU exactly), double-buffered LDS with
// prefetch-at-top + SINGLE barrier per ktile (T3 2-phase minimum), 2 waves/SIMD
// with 256-VGPR cap (launch_bounds 2nd arg behaves as blocks/CU: measured
// r2=64, r3=128 regs at 4/2 blocks).

#define N_TOK 32768
#define D_IN  1024
#define D_H   512
#define N_EXP 8

#define BM      128
#define BK      16
#define THREADS 512
#define NKT     (D_IN / BK)   // 64 k-tiles
#define WSLOTS  (NKT * 1024)  // W1 frag slots per hi/lo plane

typedef _Float16 f16;
typedef __attribute__((ext_vector_type(4)))  _Float16 f16x4;
typedef __attribute__((ext_vector_type(8)))  _Float16 f16x8;
typedef __attribute__((ext_vector_type(16))) float    f32x16;

#define MFMA(a, b, c) __builtin_amdgcn_mfma_f32_32x32x16_f16((a), (b), (c), 0, 0, 0)

#define GLOAD16(gsrc, ldst)                                                    \
    __builtin_amdgcn_global_load_lds(                                          \
        (const __attribute__((address_space(1))) void*)(gsrc),                 \
        (__attribute__((address_space(3))) void*)(ldst), 16, 0, 0)

// ---- pre-kernel: split W1 into hi/lo f16 fragments in ws (unchanged, verified) ----
__global__ void split_w1(const float* __restrict__ W1,
                         f16* __restrict__ wsH, f16* __restrict__ wsL) {
    const int s = blockIdx.x * 256 + threadIdx.x;   // 0..65535
    const int kt  = s >> 10;
    const int ctg = (s >> 6) & 15;
    const int l   = s & 63;
    const int n   = ctg * 32 + (l & 31);
    const int k   = kt * BK + (l >> 5) * 8;
    const float* src = &W1[(size_t)n * D_IN + k];
    float4 a0 = *(const float4*)src;
    float4 a1 = *(const float4*)(src + 4);
    f16x8 hi, lo;
#pragma unroll
    for (int j = 0; j < 4; ++j) {
        float v0 = ((const float*)&a0)[j];
        float v1 = ((const float*)&a1)[j];
        _Float16 h0 = (_Float16)v0, h1 = (_Float16)v1;
        hi[j] = h0;     hi[j + 4] = h1;
        lo[j] = (_Float16)(v0 - (float)h0);
        lo[j + 4] = (_Float16)(v1 - (float)h1);
    }
    *(f16x8*)&wsH[(size_t)s * 8] = hi;
    *(f16x8*)&wsL[(size_t)s * 8] = lo;
}

// ---- main kernel ----
__global__ __launch_bounds__(THREADS, 1)   // 1 block/CU -> 2 waves/SIMD -> 256-VGPR cap
void moe_router_mfma(const float* __restrict__ x,
                     const f16* __restrict__ wH,
                     const f16* __restrict__ wL,
                     const float* __restrict__ b1,
                     const float* __restrict__ W2,
                     const float* __restrict__ b2,
                     float* __restrict__ out)
{
    // A frags: [buf][hi/lo][256 slots * 8 f16]  -> 16 KB
    __shared__ __align__(16) f16 AS[2 * 2 * 2048];
    // B frags: [buf][hi 16KB | lo 16KB]         -> 64 KB (overlaid by h_s [32][512] f32)
    __shared__ __align__(16) unsigned char BB[65536];
    __shared__ __align__(16) float W2s[N_EXP * D_H];   // 16 KB
    __shared__ __align__(16) float b1s[D_H];           // 2 KB
    __shared__ float b2s[N_EXP];

    const int t    = threadIdx.x;
    const int w    = t >> 6;
    const int lane = t & 63;
    const int m0   = blockIdx.x * BM;

    // 8 accumulators: row-tile rt=0..3 x col c=0..1 (wave owns cols 2w,2w+1)
    f32x16 a0c0 = {}, a0c1 = {}, a1c0 = {}, a1c1 = {};
    f32x16 a2c0 = {}, a2c1 = {}, a3c0 = {}, a3c1 = {};

    // A staging geometry: thread t -> frag fA = t>>1 (slot = rt*64 + l),
    // quarter qA = t&1. row = rt*32 + (l&31), k = (l>>5)*8 + qA*4.
    const int fA   = t >> 1;
    const int qA   = t & 1;
    const int rowA = (fA >> 6) * 32 + (fA & 31);
    const int kA   = ((fA >> 5) & 1) * 8 + qA * 4;
    const float* xsrc = x + (size_t)(m0 + rowA) * D_IN + kA;
    const int aOff = t * 8;   // f16 offset within a plane (fA*8 + qA*4 == t*8? no)
    // NOTE: fA*8 + qA*4 == (t>>1)*8 + (t&1)*4 == t*4 + ((t>>1)*4) ... compute directly:
    const int aDst = fA * 8 + qA * 4;
    (void)aOff;

    auto stageB = [&](int kt, int buf) {
        const size_t base = (size_t)kt * 8192;   // f16 elems per ktile (1024 slots * 8)
        f16* bh = (f16*)(BB + buf * 32768);
        f16* bl = (f16*)(BB + buf * 32768 + 16384);
        GLOAD16(wH + base + (size_t)t * 8,         bh + w * 512);
        GLOAD16(wH + base + (size_t)(512 + t) * 8, bh + 4096 + w * 512);
        GLOAD16(wL + base + (size_t)t * 8,         bl + w * 512);
        GLOAD16(wL + base + (size_t)(512 + t) * 8, bl + 4096 + w * 512);
    };
    auto stageAwrite = [&](const float4& xv, int buf) {
        f16x4 hi, lo;
        float v[4] = {xv.x, xv.y, xv.z, xv.w};
#pragma unroll
        for (int j = 0; j < 4; ++j) {
            _Float16 h = (_Float16)v[j];
            hi[j] = h;
            lo[j] = (_Float16)(v[j] - (float)h);
        }
        *(f16x4*)&AS[(buf * 2 + 0) * 2048 + aDst] = hi;
        *(f16x4*)&AS[(buf * 2 + 1) * 2048 + aDst] = lo;
    };

    // ---- prologue: stage ktile 0 into buf 0 ----
    {
        float4 xv = *(const float4*)xsrc;
        stageB(0, 0);
        stageAwrite(xv, 0);
    }
    __syncthreads();

    for (int kt = 0; kt < NKT; ++kt) {
        const int cur = kt & 1;
        const int nxt = cur ^ 1;

        // prefetch next tile FIRST (x -> reg issued before B gloads so the
        // split's wait is a counted vmcnt, not a drain)
        float4 xv;
        if (kt + 1 < NKT) {
            xv = *(const float4*)(xsrc + (size_t)(kt + 1) * BK);
            stageB(kt + 1, nxt);
        }

        // ---- compute on cur ----
        const f16* ah = &AS[(cur * 2 + 0) * 2048];
        const f16* al = &AS[(cur * 2 + 1) * 2048];
        const f16* bh = (const f16*)(BB + cur * 32768);
        const f16* bl = (const f16*)(BB + cur * 32768 + 16384);

        f16x8 ah0 = *(const f16x8*)&ah[(0 * 64 + lane) * 8];
        f16x8 ah1 = *(const f16x8*)&ah[(1 * 64 + lane) * 8];
        f16x8 ah2 = *(const f16x8*)&ah[(2 * 64 + lane) * 8];
        f16x8 ah3 = *(const f16x8*)&ah[(3 * 64 + lane) * 8];
        f16x8 al0 = *(const f16x8*)&al[(0 * 64 + lane) * 8];
        f16x8 al1 = *(const f16x8*)&al[(1 * 64 + lane) * 8];
        f16x8 al2 = *(const f16x8*)&al[(2 * 64 + lane) * 8];
        f16x8 al3 = *(const f16x8*)&al[(3 * 64 + lane) * 8];
        f16x8 bh0 = *(const f16x8*)&bh[((2 * w + 0) * 64 + lane) * 8];
        f16x8 bh1 = *(const f16x8*)&bh[((2 * w + 1) * 64 + lane) * 8];
        f16x8 bl0 = *(const f16x8*)&bl[((2 * w + 0) * 64 + lane) * 8];
        f16x8 bl1 = *(const f16x8*)&bl[((2 * w + 1) * 64 + lane) * 8];

        a0c0 = MFMA(ah0, bh0, a0c0); a0c0 = MFMA(al0, bh0, a0c0); a0c0 = MFMA(ah0, bl0, a0c0);
        a1c0 = MFMA(ah1, bh0, a1c0); a1c0 = MFMA(al1, bh0, a1c0); a1c0 = MFMA(ah1, bl0, a1c0);
        a2c0 = MFMA(ah2, bh0, a2c0); a2c0 = MFMA(al2, bh0, a2c0); a2c0 = MFMA(ah2, bl0, a2c0);
        a3c0 = MFMA(ah3, bh0, a3c0); a3c0 = MFMA(al3, bh0, a3c0); a3c0 = MFMA(ah3, bl0, a3c0);
        a0c1 = MFMA(ah0, bh1, a0c1); a0c1 = MFMA(al0, bh1, a0c1); a0c1 = MFMA(ah0, bl1, a0c1);
        a1c1 = MFMA(ah1, bh1, a1c1); a1c1 = MFMA(al1, bh1, a1c1); a1c1 = MFMA(ah1, bl1, a1c1);
        a2c1 = MFMA(ah2, bh1, a2c1); a2c1 = MFMA(al2, bh1, a2c1); a2c1 = MFMA(ah2, bl1, a2c1);
        a3c1 = MFMA(ah3, bh1, a3c1); a3c1 = MFMA(al3, bh1, a3c1); a3c1 = MFMA(ah3, bl1, a3c1);

        // stage A for next tile (different buffer; safe before the barrier)
        if (kt + 1 < NKT) stageAwrite(xv, nxt);

        __syncthreads();   // one barrier per ktile (drains B gloads + A writes)
    }

    // ---- epilogue ----
    ((float4*)W2s)[t * 2]     = ((const float4*)W2)[t * 2];
    ((float4*)W2s)[t * 2 + 1] = ((const float4*)W2)[t * 2 + 1];
    if (t < D_H / 4) ((float4*)b1s)[t] = ((const float4*)b1)[t];
    if (t < N_EXP) b2s[t] = b2[t];
    __syncthreads();

    // thread's two output columns (C/D layout verified r4: col = lane&31)
    const int n0  = w * 64 + (lane & 31);
    const int n1  = n0 + 32;
    const float bn0 = b1s[n0];
    const float bn1 = b1s[n1];
    float* h_s = (float*)BB;   // [32][512] fp32 per row-tile group

    float* out_logits = out;
    float* out_w      = out + (size_t)N_TOK * N_EXP;
    float* out_i      = out_w + (size_t)N_TOK * 2;
    float* out_m      = out_i + (size_t)N_TOK * 2;

    auto reduce_rows = [&](int rt) {
#pragma unroll
        for (int rr2 = 0; rr2 < 4; ++rr2) {
            const int rl   = w * 4 + rr2;            // 8 waves x 4 = 32 rows
            const int grow = m0 + rt * 32 + rl;
            float4 ha = *(const float4*)&h_s[rl * 512 + lane * 4];
            float4 hb = *(const float4*)&h_s[rl * 512 + 256 + lane * 4];
            float v1 = -3.4e38f, v2 = -3.4e38f;
            int   i1 = 0, i2 = 0;
            float pls[8];
#pragma unroll
            for (int e = 0; e < N_EXP; ++e) {
                float4 wa = *(const float4*)&W2s[e * D_H + lane * 4];
                float4 wb = *(const float4*)&W2s[e * D_H + 256 + lane * 4];
                float s = ha.x * wa.x;
                s = fmaf(ha.y, wa.y, s);
                s = fmaf(ha.z, wa.z, s);
                s = fmaf(ha.w, wa.w, s);
                s = fmaf(hb.x, wb.x, s);
                s = fmaf(hb.y, wb.y, s);
                s = fmaf(hb.z, wb.z, s);
                s = fmaf(hb.w, wb.w, s);
#pragma unroll
                for (int off = 1; off < 64; off <<= 1)
                    s += __shfl_xor(s, off);
                s += b2s[e];
                pls[e] = s;
                if (s > v1)      { v2 = v1; i2 = i1; v1 = s; i1 = e; }
                else if (s > v2) { v2 = s;  i2 = e; }
            }
            const float rr   = expf(v2 - v1);
            const float wden = 1.f / (1.f + rr);
            if (lane == 0) {
                float4 lo4 = {pls[0], pls[1], pls[2], pls[3]};
                float4 hi4 = {pls[4], pls[5], pls[6], pls[7]};
                *(float4*)&out_logits[(size_t)grow * N_EXP]     = lo4;
                *(float4*)&out_logits[(size_t)grow * N_EXP + 4] = hi4;
                float2 wv = {wden, rr * wden};
                *(float2*)&out_w[(size_t)grow * 2] = wv;
                float2 iv = {(float)i1, (float)i2};
                *(float2*)&out_i[(size_t)grow * 2] = iv;
            }
            if (lane < 16) {
                const int e   = lane >> 1;
                const int kk  = lane & 1;
                const int sel = kk ? i2 : i1;
                out_m[((size_t)(e * 2 + kk)) * N_TOK + grow] = (sel == e) ? 1.0f : 0.0f;
            }
        }
    };

    // C/D row map (verified r4): in-tile row = (rr&3) + 8*(rr>>2) + 4*(lane>>5)
#define DO_GROUP(AC0, AC1, RT) do {                                            \
        _Pragma("unroll")                                                      \
        for (int rr = 0; rr < 16; ++rr) {                                      \
            const int rl = (rr & 3) + 8 * (rr >> 2) + 4 * (lane >> 5);         \
            h_s[rl * 512 + n0] = AC0[rr] + bn0;                                \
            h_s[rl * 512 + n1] = AC1[rr] + bn1;                                \
        }                                                                      \
        __syncthreads();                                                       \
        reduce_rows(RT);                                                       \
        __syncthreads();                                                       \
    } while (0)

    DO_GROUP(a0c0, a0c1, 0);
    DO_GROUP(a1c0, a1c1, 1);
    DO_GROUP(a2c0, a2c1, 2);
    DO_GROUP(a3c0, a3c1, 3);
#undef DO_GROUP
}

extern "C" void kernel_launch(void* const* d_in, const int* in_sizes, int n_in,
                              void* d_out, int out_size, void* d_ws, size_t ws_size,
                              hipStream_t stream) {
    const float* x  = (const float*)d_in[0];
    const float* W1 = (const float*)d_in[1];
    const float* b1 = (const float*)d_in[2];
    const float* W2 = (const float*)d_in[3];
    const float* b2 = (const float*)d_in[4];
    float* out = (float*)d_out;

    f16* wsH = (f16*)d_ws;                       // 1 MB
    f16* wsL = wsH + (size_t)WSLOTS * 8;         // 1 MB

    split_w1<<<WSLOTS / 256, 256, 0, stream>>>(W1, wsH, wsL);
    moe_router_mfma<<<N_TOK / BM, THREADS, 0, stream>>>(x, wsH, wsL, b1, W2, b2, out);
}

// Round 6
// 130.635 us; speedup vs baseline: 17.9091x; 1.0818x over previous
//
#include <hip/hip_runtime.h>
#include <math.h>

// MoE router on MFMA: logits = (x @ W1^T + b1) @ W2^T + b2; softmax; top-2; masks.
// N=32768, D=1024, D_H=512, E=8, K=2.
//
// Split-fp16: x = xh+xl, W1 = wh+wl; h = xh*wh + xl*wh + xh*wl (3 MFMA passes,
// fp32 acc). W1 pre-split/pre-packed into 32x32x16 fragment order in d_ws (r4).
//
// Round-6: B frags bypass LDS -> per-wave registers (B is wave-private; LDS
// sharing only pays for A). 1-ktile register prefetch for B via unroll-x2
// named double-buffer (rule #20). A stays LDS-double-buffered (shared by all
// waves). setprio(1) around MFMA clusters + mid-ktile raw s_barrier for wave
// role-split (T5/T3). 1 block/CU, 2 waves/SIMD, 256-VGPR cap.

#define N_TOK 32768
#define D_IN  1024
#define D_H   512
#define N_EXP 8

#define BM      128
#define BK      16
#define THREADS 512
#define NKT     (D_IN / BK)   // 64 k-tiles
#define WSLOTS  (NKT * 1024)  // W1 frag slots per hi/lo plane

typedef _Float16 f16;
typedef __attribute__((ext_vector_type(4)))  _Float16 f16x4;
typedef __attribute__((ext_vector_type(8)))  _Float16 f16x8;
typedef __attribute__((ext_vector_type(16))) float    f32x16;

#define MFMA(a, b, c) __builtin_amdgcn_mfma_f32_32x32x16_f16((a), (b), (c), 0, 0, 0)

// ---- pre-kernel: split W1 into hi/lo f16 fragments in ws (verified r4/r5) ----
__global__ void split_w1(const float* __restrict__ W1,
                         f16* __restrict__ wsH, f16* __restrict__ wsL) {
    const int s = blockIdx.x * 256 + threadIdx.x;   // 0..65535
    const int kt  = s >> 10;
    const int ctg = (s >> 6) & 15;
    const int l   = s & 63;
    const int n   = ctg * 32 + (l & 31);
    const int k   = kt * BK + (l >> 5) * 8;
    const float* src = &W1[(size_t)n * D_IN + k];
    float4 a0 = *(const float4*)src;
    float4 a1 = *(const float4*)(src + 4);
    f16x8 hi, lo;
#pragma unroll
    for (int j = 0; j < 4; ++j) {
        float v0 = ((const float*)&a0)[j];
        float v1 = ((const float*)&a1)[j];
        _Float16 h0 = (_Float16)v0, h1 = (_Float16)v1;
        hi[j] = h0;     hi[j + 4] = h1;
        lo[j] = (_Float16)(v0 - (float)h0);
        lo[j + 4] = (_Float16)(v1 - (float)h1);
    }
    *(f16x8*)&wsH[(size_t)s * 8] = hi;
    *(f16x8*)&wsL[(size_t)s * 8] = lo;
}

// ---- main kernel ----
__global__ __launch_bounds__(THREADS, 1)   // 1 block/CU -> 2 waves/SIMD -> 256-VGPR cap
void moe_router_mfma(const float* __restrict__ x,
                     const f16* __restrict__ wH,
                     const f16* __restrict__ wL,
                     const float* __restrict__ b1,
                     const float* __restrict__ W2,
                     const float* __restrict__ b2,
                     float* __restrict__ out)
{
    __shared__ __align__(16) f16   AS[2 * 2 * 2048];     // A frags dbuf: 16 KB
    __shared__ __align__(16) float h_s[32 * 512];        // epilogue h: 64 KB
    __shared__ __align__(16) float W2s[N_EXP * D_H];     // 16 KB
    __shared__ __align__(16) float b1s[D_H];             // 2 KB
    __shared__ float b2s[N_EXP];

    const int t    = threadIdx.x;
    const int w    = t >> 6;
    const int lane = t & 63;
    const int m0   = blockIdx.x * BM;

    // 8 accumulators: row-tile rt=0..3 x col c=0..1 (wave owns cols 2w,2w+1)
    f32x16 a0c0 = {}, a0c1 = {}, a1c0 = {}, a1c1 = {};
    f32x16 a2c0 = {}, a2c1 = {}, a3c0 = {}, a3c1 = {};

    // A staging geometry (verified r4/r5): thread t -> frag fA=t>>1, quarter qA=t&1.
    const int fA   = t >> 1;
    const int qA   = t & 1;
    const int rowA = (fA >> 6) * 32 + (fA & 31);
    const int kA   = ((fA >> 5) & 1) * 8 + qA * 4;
    const float* xsrc = x + (size_t)(m0 + rowA) * D_IN + kA;
    const int aDst = fA * 8 + qA * 4;

    // B frag offsets for this wave (f16 elements within one ktile plane)
    const size_t bOff0 = (size_t)(2 * w + 0) * 512 + (size_t)lane * 8;
    const size_t bOff1 = (size_t)(2 * w + 1) * 512 + (size_t)lane * 8;

    auto stageAwrite = [&](const float4& xv, int buf) {
        f16x4 hi, lo;
        float v[4] = {xv.x, xv.y, xv.z, xv.w};
#pragma unroll
        for (int j = 0; j < 4; ++j) {
            _Float16 h = (_Float16)v[j];
            hi[j] = h;
            lo[j] = (_Float16)(v[j] - (float)h);
        }
        *(f16x4*)&AS[(buf * 2 + 0) * 2048 + aDst] = hi;
        *(f16x4*)&AS[(buf * 2 + 1) * 2048 + aDst] = lo;
    };

    // ---- prologue: B regs + A LDS for ktile 0 ----
    f16x8 Bh0A = *(const f16x8*)(wH + bOff0);
    f16x8 Bh1A = *(const f16x8*)(wH + bOff1);
    f16x8 Bl0A = *(const f16x8*)(wL + bOff0);
    f16x8 Bl1A = *(const f16x8*)(wL + bOff1);
    f16x8 Bh0B, Bh1B, Bl0B, Bl1B;
    {
        float4 xv = *(const float4*)xsrc;
        stageAwrite(xv, 0);
    }
    __syncthreads();

    // One ktile body. BUF = A-buffer of this ktile; B cur regs named in;
    // B next regs named out (loaded here, consumed next body).
#define BODY(BUF, KT, BH0, BH1, BL0, BL1, NH0, NH1, NL0, NL1) do {             \
        float4 xnxt = {0.f, 0.f, 0.f, 0.f};                                    \
        if ((KT) + 1 < NKT) {                                                  \
            const size_t nb = (size_t)((KT) + 1) * 8192;                       \
            NH0 = *(const f16x8*)(wH + nb + bOff0);                            \
            NH1 = *(const f16x8*)(wH + nb + bOff1);                            \
            NL0 = *(const f16x8*)(wL + nb + bOff0);                            \
            NL1 = *(const f16x8*)(wL + nb + bOff1);                            \
            xnxt = *(const float4*)(xsrc + (size_t)((KT) + 1) * BK);           \
        }                                                                      \
        const f16* ah = &AS[((BUF) * 2 + 0) * 2048];                           \
        const f16* al = &AS[((BUF) * 2 + 1) * 2048];                           \
        f16x8 ah0 = *(const f16x8*)&ah[(0 * 64 + lane) * 8];                   \
        f16x8 al0 = *(const f16x8*)&al[(0 * 64 + lane) * 8];                   \
        f16x8 ah1 = *(const f16x8*)&ah[(1 * 64 + lane) * 8];                   \
        f16x8 al1 = *(const f16x8*)&al[(1 * 64 + lane) * 8];                   \
        f16x8 ah2 = *(const f16x8*)&ah[(2 * 64 + lane) * 8];                   \
        f16x8 al2 = *(const f16x8*)&al[(2 * 64 + lane) * 8];                   \
        f16x8 ah3 = *(const f16x8*)&ah[(3 * 64 + lane) * 8];                   \
        f16x8 al3 = *(const f16x8*)&al[(3 * 64 + lane) * 8];                   \
        __builtin_amdgcn_s_setprio(1);                                         \
        a0c0 = MFMA(ah0, BH0, a0c0); a0c0 = MFMA(al0, BH0, a0c0);              \
        a0c0 = MFMA(ah0, BL0, a0c0);                                           \
        a1c0 = MFMA(ah1, BH0, a1c0); a1c0 = MFMA(al1, BH0, a1c0);              \
        a1c0 = MFMA(ah1, BL0, a1c0);                                           \
        a2c0 = MFMA(ah2, BH0, a2c0); a2c0 = MFMA(al2, BH0, a2c0);              \
        a2c0 = MFMA(ah2, BL0, a2c0);                                           \
        a3c0 = MFMA(ah3, BH0, a3c0); a3c0 = MFMA(al3, BH0, a3c0);              \
        a3c0 = MFMA(ah3, BL0, a3c0);                                           \
        __builtin_amdgcn_s_setprio(0);                                         \
        __builtin_amdgcn_s_barrier();                                          \
        __builtin_amdgcn_s_setprio(1);                                         \
        a0c1 = MFMA(ah0, BH1, a0c1); a0c1 = MFMA(al0, BH1, a0c1);              \
        a0c1 = MFMA(ah0, BL1, a0c1);                                           \
        a1c1 = MFMA(ah1, BH1, a1c1); a1c1 = MFMA(al1, BH1, a1c1);              \
        a1c1 = MFMA(ah1, BL1, a1c1);                                           \
        a2c1 = MFMA(ah2, BH1, a2c1); a2c1 = MFMA(al2, BH1, a2c1);              \
        a2c1 = MFMA(ah2, BL1, a2c1);                                           \
        a3c1 = MFMA(ah3, BH1, a3c1); a3c1 = MFMA(al3, BH1, a3c1);              \
        a3c1 = MFMA(ah3, BL1, a3c1);                                           \
        __builtin_amdgcn_s_setprio(0);                                         \
        if ((KT) + 1 < NKT) stageAwrite(xnxt, (BUF) ^ 1);                      \
        __syncthreads();                                                       \
    } while (0)

    for (int kt = 0; kt < NKT; kt += 2) {
        BODY(0, kt,     Bh0A, Bh1A, Bl0A, Bl1A, Bh0B, Bh1B, Bl0B, Bl1B);
        BODY(1, kt + 1, Bh0B, Bh1B, Bl0B, Bl1B, Bh0A, Bh1A, Bl0A, Bl1A);
    }
#undef BODY

    // ---- epilogue (verified r4/r5) ----
    ((float4*)W2s)[t * 2]     = ((const float4*)W2)[t * 2];
    ((float4*)W2s)[t * 2 + 1] = ((const float4*)W2)[t * 2 + 1];
    if (t < D_H / 4) ((float4*)b1s)[t] = ((const float4*)b1)[t];
    if (t < N_EXP) b2s[t] = b2[t];
    __syncthreads();

    const int n0  = w * 64 + (lane & 31);   // C/D layout: col = lane&31
    const int n1  = n0 + 32;
    const float bn0 = b1s[n0];
    const float bn1 = b1s[n1];

    float* out_logits = out;
    float* out_w      = out + (size_t)N_TOK * N_EXP;
    float* out_i      = out_w + (size_t)N_TOK * 2;
    float* out_m      = out_i + (size_t)N_TOK * 2;

    auto reduce_rows = [&](int rt) {
#pragma unroll
        for (int rr2 = 0; rr2 < 4; ++rr2) {
            const int rl   = w * 4 + rr2;            // 8 waves x 4 = 32 rows
            const int grow = m0 + rt * 32 + rl;
            float4 ha = *(const float4*)&h_s[rl * 512 + lane * 4];
            float4 hb = *(const float4*)&h_s[rl * 512 + 256 + lane * 4];
            float v1 = -3.4e38f, v2 = -3.4e38f;
            int   i1 = 0, i2 = 0;
            float pls[8];
#pragma unroll
            for (int e = 0; e < N_EXP; ++e) {
                float4 wa = *(const float4*)&W2s[e * D_H + lane * 4];
                float4 wb = *(const float4*)&W2s[e * D_H + 256 + lane * 4];
                float s = ha.x * wa.x;
                s = fmaf(ha.y, wa.y, s);
                s = fmaf(ha.z, wa.z, s);
                s = fmaf(ha.w, wa.w, s);
                s = fmaf(hb.x, wb.x, s);
                s = fmaf(hb.y, wb.y, s);
                s = fmaf(hb.z, wb.z, s);
                s = fmaf(hb.w, wb.w, s);
#pragma unroll
                for (int off = 1; off < 64; off <<= 1)
                    s += __shfl_xor(s, off);
                s += b2s[e];
                pls[e] = s;
                if (s > v1)      { v2 = v1; i2 = i1; v1 = s; i1 = e; }
                else if (s > v2) { v2 = s;  i2 = e; }
            }
            const float rr   = expf(v2 - v1);
            const float wden = 1.f / (1.f + rr);
            if (lane == 0) {
                float4 lo4 = {pls[0], pls[1], pls[2], pls[3]};
                float4 hi4 = {pls[4], pls[5], pls[6], pls[7]};
                *(float4*)&out_logits[(size_t)grow * N_EXP]     = lo4;
                *(float4*)&out_logits[(size_t)grow * N_EXP + 4] = hi4;
                float2 wv = {wden, rr * wden};
                *(float2*)&out_w[(size_t)grow * 2] = wv;
                float2 iv = {(float)i1, (float)i2};
                *(float2*)&out_i[(size_t)grow * 2] = iv;
            }
            if (lane < 16) {
                const int e   = lane >> 1;
                const int kk  = lane & 1;
                const int sel = kk ? i2 : i1;
                out_m[((size_t)(e * 2 + kk)) * N_TOK + grow] = (sel == e) ? 1.0f : 0.0f;
            }
        }
    };

    // C/D row map (verified): in-tile row = (rr&3) + 8*(rr>>2) + 4*(lane>>5)
#define DO_GROUP(AC0, AC1, RT) do {                                            \
        _Pragma("unroll")                                                      \
        for (int rr = 0; rr < 16; ++rr) {                                      \
            const int rl = (rr & 3) + 8 * (rr >> 2) + 4 * (lane >> 5);         \
            h_s[rl * 512 + n0] = AC0[rr] + bn0;                                \
            h_s[rl * 512 + n1] = AC1[rr] + bn1;                                \
        }                                                                      \
        __syncthreads();                                                       \
        reduce_rows(RT);                                                       \
        __syncthreads();                                                       \
    } while (0)

    DO_GROUP(a0c0, a0c1, 0);
    DO_GROUP(a1c0, a1c1, 1);
    DO_GROUP(a2c0, a2c1, 2);
    DO_GROUP(a3c0, a3c1, 3);
#undef DO_GROUP
}

extern "C" void kernel_launch(void* const* d_in, const int* in_sizes, int n_in,
                              void* d_out, int out_size, void* d_ws, size_t ws_size,
                              hipStream_t stream) {
    const float* x  = (const float*)d_in[0];
    const float* W1 = (const float*)d_in[1];
    const float* b1 = (const float*)d_in[2];
    const float* W2 = (const float*)d_in[3];
    const float* b2 = (const float*)d_in[4];
    float* out = (float*)d_out;

    f16* wsH = (f16*)d_ws;                       // 1 MB
    f16* wsL = wsH + (size_t)WSLOTS * 8;         // 1 MB

    split_w1<<<WSLOTS / 256, 256, 0, stream>>>(W1, wsH, wsL);
    moe_router_mfma<<<N_TOK / BM, THREADS, 0, stream>>>(x, wsH, wsL, b1, W2, b2, out);
}